// Round 6
// baseline (545.755 us; speedup 1.0000x reference)
//
#include <hip/hip_runtime.h>
#include <math.h>

constexpr int NN     = 100000;  // nodes
constexpr int DIN    = 128;
constexpr int DH     = 16;      // hidden
constexpr int NC     = 40;      // classes
constexpr int RNG    = 128;     // nodes per bucket (dst >> 7); dl fits 7 bits
constexpr int NBUCK  = (NN + RNG - 1) / RNG;   // 782
constexpr int NBUCKP = 1024;    // padded (power of 2 for scan)
constexpr int CHUNK  = 8192;    // edges per binscatter workgroup

__device__ __forceinline__ unsigned short f32_to_bf16(float f) {
    unsigned b = __float_as_uint(f);
    return (unsigned short)((b + 0x7FFFu + ((b >> 16) & 1u)) >> 16);
}
__device__ __forceinline__ float bf16u_to_f32(unsigned short u) {
    return __uint_as_float(((unsigned)u) << 16);
}

// ---------- pass 1: global bucket histogram ----------
__global__ void k_hist(const int* __restrict__ dst, int E, int al, int* __restrict__ ghist) {
    __shared__ int lh[NBUCKP];
    for (int i = threadIdx.x; i < NBUCKP; i += blockDim.x) lh[i] = 0;
    __syncthreads();
    int nv = al ? (E >> 2) : 0;
    const int4* d4 = (const int4*)dst;
    int i  = blockIdx.x * blockDim.x + threadIdx.x;
    int st = gridDim.x * blockDim.x;
    for (int k = i; k < nv; k += st) {
        int4 v = d4[k];
        atomicAdd(&lh[v.x >> 7], 1);
        atomicAdd(&lh[v.y >> 7], 1);
        atomicAdd(&lh[v.z >> 7], 1);
        atomicAdd(&lh[v.w >> 7], 1);
    }
    for (int e = 4 * nv + i; e < E; e += st) atomicAdd(&lh[dst[e] >> 7], 1);
    __syncthreads();
    for (int j = threadIdx.x; j < NBUCKP; j += blockDim.x) {
        int v = lh[j];
        if (v) atomicAdd(&ghist[j], v);
    }
}

// ---------- pass 2: exclusive scan of bucket counts (one WG, 1024 threads) ----------
__global__ __launch_bounds__(1024) void k_scan(const int* __restrict__ ghist,
                                               int* __restrict__ bbase,
                                               int* __restrict__ gcursor) {
    __shared__ int s[NBUCKP];
    int t = threadIdx.x;
    s[t] = ghist[t];
    __syncthreads();
    for (int o = 1; o < NBUCKP; o <<= 1) {
        int v = (t >= o) ? s[t - o] : 0;
        __syncthreads();
        s[t] += v;
        __syncthreads();
    }
    int excl = t ? s[t - 1] : 0;
    bbase[t]   = excl;
    gcursor[t] = excl;
    if (t == NBUCKP - 1) bbase[NBUCKP] = s[t];
}

// ---------- pass 3: LDS counting-sort per chunk, coalesced writeout ----------
__global__ __launch_bounds__(256) void k_binscatter(
    const int* __restrict__ src, const int* __restrict__ dst, int E, int al,
    int* __restrict__ gcursor, unsigned* __restrict__ packed)
{
    __shared__ unsigned       spack[CHUNK];     // 32 KB
    __shared__ unsigned short sbuck[CHUNK];     // 16 KB
    __shared__ int lhist[NBUCKP];               // 4 KB (hist -> cursor)
    __shared__ int lbase[NBUCKP];               // 4 KB (global offset per bucket)
    __shared__ int part[256];

    int e0 = blockIdx.x * CHUNK;
    int cn = E - e0; if (cn > CHUNK) cn = CHUNK;
    int t = threadIdx.x;

    for (int i = t; i < NBUCKP; i += 256) lhist[i] = 0;
    __syncthreads();

    int nv = al ? (cn >> 2) : 0;
    const int4* dsp = (const int4*)(dst + e0);
    const int4* ssp = (const int4*)(src + e0);

    // local histogram
    for (int i = t; i < nv; i += 256) {
        int4 v = dsp[i];
        atomicAdd(&lhist[v.x >> 7], 1);
        atomicAdd(&lhist[v.y >> 7], 1);
        atomicAdd(&lhist[v.z >> 7], 1);
        atomicAdd(&lhist[v.w >> 7], 1);
    }
    for (int i = 4 * nv + t; i < cn; i += 256) atomicAdd(&lhist[dst[e0 + i] >> 7], 1);
    __syncthreads();

    // in-block exclusive scan (each thread owns 4 buckets) + global range claim
    int b4 = t * 4;
    int a0 = lhist[b4], a1 = lhist[b4 + 1], a2 = lhist[b4 + 2], a3 = lhist[b4 + 3];
    part[t] = a0 + a1 + a2 + a3;
    __syncthreads();
    for (int o = 1; o < 256; o <<= 1) {
        int v = (t >= o) ? part[t - o] : 0;
        __syncthreads();
        part[t] += v;
        __syncthreads();
    }
    int pex = t ? part[t - 1] : 0;
    int l0 = pex, l1 = pex + a0, l2 = l1 + a1, l3 = l2 + a2;
    lbase[b4 + 0] = (a0 ? atomicAdd(&gcursor[b4 + 0], a0) : 0) - l0;
    lbase[b4 + 1] = (a1 ? atomicAdd(&gcursor[b4 + 1], a1) : 0) - l1;
    lbase[b4 + 2] = (a2 ? atomicAdd(&gcursor[b4 + 2], a2) : 0) - l2;
    lbase[b4 + 3] = (a3 ? atomicAdd(&gcursor[b4 + 3], a3) : 0) - l3;
    lhist[b4 + 0] = l0; lhist[b4 + 1] = l1; lhist[b4 + 2] = l2; lhist[b4 + 3] = l3;
    __syncthreads();

    // counting-sort into LDS
    for (int i = t; i < nv; i += 256) {
        int4 dv = dsp[i];
        int4 sv = ssp[i];
        int d, b, pos;
        d = dv.x; b = d >> 7; pos = atomicAdd(&lhist[b], 1);
        spack[pos] = ((unsigned)(d & 127) << 20) | (unsigned)sv.x; sbuck[pos] = (unsigned short)b;
        d = dv.y; b = d >> 7; pos = atomicAdd(&lhist[b], 1);
        spack[pos] = ((unsigned)(d & 127) << 20) | (unsigned)sv.y; sbuck[pos] = (unsigned short)b;
        d = dv.z; b = d >> 7; pos = atomicAdd(&lhist[b], 1);
        spack[pos] = ((unsigned)(d & 127) << 20) | (unsigned)sv.z; sbuck[pos] = (unsigned short)b;
        d = dv.w; b = d >> 7; pos = atomicAdd(&lhist[b], 1);
        spack[pos] = ((unsigned)(d & 127) << 20) | (unsigned)sv.w; sbuck[pos] = (unsigned short)b;
    }
    for (int i = 4 * nv + t; i < cn; i += 256) {
        int d = dst[e0 + i], s = src[e0 + i];
        int b = d >> 7; int pos = atomicAdd(&lhist[b], 1);
        spack[pos] = ((unsigned)(d & 127) << 20) | (unsigned)s; sbuck[pos] = (unsigned short)b;
    }
    __syncthreads();

    // writeout in sorted order: runs of same bucket -> consecutive global addrs
    for (int i = t; i < cn; i += 256)
        packed[lbase[sbuck[i]] + i] = spack[i];
}

// ---------- projection: LDS x-tile, coalesced; p1l -> bf16, p1r -> f32 ----------
__global__ __launch_bounds__(256) void k_proj(
    const float* __restrict__ x, const float* __restrict__ W1l, const float* __restrict__ W1r,
    unsigned short* __restrict__ p1l16, float* __restrict__ p1r)
{
    __shared__ float sX[64][DIN + 1];   // 33 KB
    __shared__ float sW[DIN][32];       // 16 KB: cols 0-15 W1l, 16-31 W1r
    int t  = threadIdx.x;
    int n0 = blockIdx.x * 64;
    for (int i = t; i < DIN * 32; i += 256) {
        int k = i >> 5, j = i & 31;
        sW[k][j] = (j < DH) ? W1l[k * DH + j] : W1r[k * DH + (j - DH)];
    }
    int nrow = NN - n0; if (nrow > 64) nrow = 64;
    const float4* xg = (const float4*)(x + (size_t)n0 * DIN);
    for (int i = t; i < nrow * (DIN / 4); i += 256) {
        float4 v = xg[i];
        int n = i >> 5, k = (i & 31) * 4;
        sX[n][k] = v.x; sX[n][k + 1] = v.y; sX[n][k + 2] = v.z; sX[n][k + 3] = v.w;
    }
    __syncthreads();
    int n = t & 63, jg = t >> 6;
    if (n0 + n >= NN) return;
    float acc[8];
    #pragma unroll
    for (int j = 0; j < 8; ++j) acc[j] = 0.f;
    const int j0 = jg * 8;
    for (int k = 0; k < DIN; ++k) {
        float xv = sX[n][k];                       // banks (n+k)%32: 2-way, free
        const float4* wr = (const float4*)&sW[k][j0];  // wave-uniform -> broadcast
        float4 w0 = wr[0], w1 = wr[1];
        acc[0] = fmaf(xv, w0.x, acc[0]); acc[1] = fmaf(xv, w0.y, acc[1]);
        acc[2] = fmaf(xv, w0.z, acc[2]); acc[3] = fmaf(xv, w0.w, acc[3]);
        acc[4] = fmaf(xv, w1.x, acc[4]); acc[5] = fmaf(xv, w1.y, acc[5]);
        acc[6] = fmaf(xv, w1.z, acc[6]); acc[7] = fmaf(xv, w1.w, acc[7]);
    }
    size_t nn = (size_t)(n0 + n);
    if (jg < 2) {
        unsigned u0 = (unsigned)f32_to_bf16(acc[0]) | ((unsigned)f32_to_bf16(acc[1]) << 16);
        unsigned u1 = (unsigned)f32_to_bf16(acc[2]) | ((unsigned)f32_to_bf16(acc[3]) << 16);
        unsigned u2 = (unsigned)f32_to_bf16(acc[4]) | ((unsigned)f32_to_bf16(acc[5]) << 16);
        unsigned u3 = (unsigned)f32_to_bf16(acc[6]) | ((unsigned)f32_to_bf16(acc[7]) << 16);
        *(uint4*)(p1l16 + nn * DH + jg * 8) = make_uint4(u0, u1, u2, u3);
    } else {
        float* pp = p1r + nn * DH + (jg - 2) * 8;
        *(float4*)pp       = make_float4(acc[0], acc[1], acc[2], acc[3]);
        *(float4*)(pp + 4) = make_float4(acc[4], acc[5], acc[6], acc[7]);
    }
}

// ---------- layer-1 aggregate: lane-per-(edge,dim), 16 consecutive banks/edge ----------
__global__ __launch_bounds__(256) void k_agg1(
    const int* __restrict__ bbase, const unsigned* __restrict__ packed,
    const unsigned short* __restrict__ p1l16, const float* __restrict__ p1r,
    const float* __restrict__ b1,
    float* __restrict__ h, unsigned short* __restrict__ h16, float* __restrict__ invdeg)
{
    __shared__ float agg[RNG][DH + 1];   // pad 17: edge's 16 lanes -> 16 consecutive banks
    __shared__ int   ldeg[RNG];
    int b  = blockIdx.x;
    int n0 = b * RNG;
    int nr = NN - n0; if (nr > RNG) nr = RNG;
    int t = threadIdx.x;
    for (int i = t; i < RNG * (DH + 1); i += 256) (&agg[0][0])[i] = 0.f;
    for (int i = t; i < RNG; i += 256) ldeg[i] = 0;
    __syncthreads();
    int s0 = bbase[b], s1 = bbase[b + 1];
    int grp = t >> 4, d = t & 15;        // 16 edge-groups x 16 dim-lanes
    int tt = s0 + grp;
    for (; tt + 16 < s1; tt += 32) {     // unroll x2 for ILP
        unsigned pA = packed[tt];
        unsigned pB = packed[tt + 16];
        float vA = bf16u_to_f32(p1l16[(size_t)(pA & 0x1FFFFu) * DH + d]);
        float vB = bf16u_to_f32(p1l16[(size_t)(pB & 0x1FFFFu) * DH + d]);
        atomicAdd(&agg[pA >> 20][d], vA);
        atomicAdd(&agg[pB >> 20][d], vB);
        if (d == 0) { atomicAdd(&ldeg[pA >> 20], 1); atomicAdd(&ldeg[pB >> 20], 1); }
    }
    if (tt < s1) {
        unsigned p = packed[tt];
        float v = bf16u_to_f32(p1l16[(size_t)(p & 0x1FFFFu) * DH + d]);
        atomicAdd(&agg[p >> 20][d], v);
        if (d == 0) atomicAdd(&ldeg[p >> 20], 1);
    }
    __syncthreads();
    for (int i = t; i < nr * DH; i += 256) {
        int nl = i >> 4, dd = i & 15;
        float inv = 1.0f / fmaxf((float)ldeg[nl], 1.0f);
        size_t n = (size_t)(n0 + nl);
        float v = fmaf(agg[nl][dd], inv, b1[dd] + p1r[n * DH + dd]);
        v = fmaxf(v, 0.f);
        h[n * DH + dd]   = v;
        h16[n * DH + dd] = f32_to_bf16(v);
        if (dd == 0) invdeg[n] = inv;
    }
}

// ---------- layer-2 aggregate + linear + log_softmax ----------
__global__ __launch_bounds__(256) void k_final(
    const int* __restrict__ bbase, const unsigned* __restrict__ packed,
    const unsigned short* __restrict__ h16, const float* __restrict__ h,
    const float* __restrict__ invdeg,
    const float* __restrict__ W2l, const float* __restrict__ b2,
    const float* __restrict__ W2r, float* __restrict__ out)
{
    __shared__ float agg[RNG][DH + 1];
    __shared__ float hloc[RNG][DH];
    __shared__ float sW[2 * DH * NC + NC];   // W2l | W2r | b2
    int t = threadIdx.x;
    for (int i = t; i < DH * NC; i += 256) { sW[i] = W2l[i]; sW[DH * NC + i] = W2r[i]; }
    if (t < NC) sW[2 * DH * NC + t] = b2[t];
    int b  = blockIdx.x;
    int n0 = b * RNG;
    int nr = NN - n0; if (nr > RNG) nr = RNG;
    for (int i = t; i < RNG * (DH + 1); i += 256) (&agg[0][0])[i] = 0.f;
    for (int i = t; i < nr * DH; i += 256) (&hloc[0][0])[i] = h[(size_t)n0 * DH + i];
    __syncthreads();
    int s0 = bbase[b], s1 = bbase[b + 1];
    int grp = t >> 4, d = t & 15;
    int tt = s0 + grp;
    for (; tt + 16 < s1; tt += 32) {
        unsigned pA = packed[tt];
        unsigned pB = packed[tt + 16];
        float vA = bf16u_to_f32(h16[(size_t)(pA & 0x1FFFFu) * DH + d]);
        float vB = bf16u_to_f32(h16[(size_t)(pB & 0x1FFFFu) * DH + d]);
        atomicAdd(&agg[pA >> 20][d], vA);
        atomicAdd(&agg[pB >> 20][d], vB);
    }
    if (tt < s1) {
        unsigned p = packed[tt];
        float v = bf16u_to_f32(h16[(size_t)(p & 0x1FFFFu) * DH + d]);
        atomicAdd(&agg[p >> 20][d], v);
    }
    __syncthreads();
    int wv = t >> 6, lane = t & 63;
    for (int nl = wv; nl < nr; nl += 4) {
        size_t n = (size_t)(n0 + nl);
        float inv = invdeg[n];
        int j = (lane < NC) ? lane : 0;
        float o = sW[2 * DH * NC + j];
        #pragma unroll
        for (int k = 0; k < DH; ++k) {
            float ak = agg[nl][k] * inv;   // same-address LDS broadcast
            float hk = hloc[nl][k];
            o = fmaf(ak, sW[k * NC + j],           o);
            o = fmaf(hk, sW[DH * NC + k * NC + j], o);
        }
        float mx = (lane < NC) ? o : -INFINITY;
        #pragma unroll
        for (int m = 32; m; m >>= 1) mx = fmaxf(mx, __shfl_xor(mx, m));
        float ex = (lane < NC) ? __expf(o - mx) : 0.f;
        float ss = ex;
        #pragma unroll
        for (int m = 32; m; m >>= 1) ss += __shfl_xor(ss, m);
        if (lane < NC) out[n * NC + lane] = o - mx - __logf(ss);
    }
}

// ---------------- launch ----------------

extern "C" void kernel_launch(void* const* d_in, const int* in_sizes, int n_in,
                              void* d_out, int out_size, void* d_ws, size_t ws_size,
                              hipStream_t stream) {
    const float* x   = (const float*)d_in[0];
    const int*   ei  = (const int*)d_in[1];   // [2, E] int32
    const float* W1l = (const float*)d_in[2];
    const float* b1  = (const float*)d_in[3];
    const float* W1r = (const float*)d_in[4];
    const float* W2l = (const float*)d_in[5];
    const float* b2  = (const float*)d_in[6];
    const float* W2r = (const float*)d_in[7];
    float* out = (float*)d_out;

    const int E = in_sizes[1] / 2;
    const int* src = ei;
    const int* dst = ei + E;
    const int al = ((E & 3) == 0) ? 1 : 0;   // int4 paths need dst=ei+E 16B-aligned

    // ws (4B words): ghist[1024] | gcursor[1024] | bbase[1032] | invdeg[NN] |
    //                packed[E] | p1r[16N] | h[16N] | p1l16(8N words) | h16(8N words)
    int* ghist   = (int*)d_ws;
    int* gcursor = ghist + NBUCKP;
    int* bbase   = gcursor + NBUCKP;
    float* invdeg = (float*)(bbase + NBUCKP + 8);
    unsigned* packed = (unsigned*)(invdeg + NN);
    float* p1r = (float*)(packed + E);
    float* h   = p1r + (size_t)NN * DH;
    unsigned short* p1l16 = (unsigned short*)(h + (size_t)NN * DH);
    unsigned short* h16   = p1l16 + (size_t)NN * DH;

    hipMemsetAsync(ghist, 0, NBUCKP * sizeof(int), stream);

    k_hist      <<<256, 256, 0, stream>>>(dst, E, al, ghist);
    k_scan      <<<1, NBUCKP, 0, stream>>>(ghist, bbase, gcursor);
    k_binscatter<<<(E + CHUNK - 1) / CHUNK, 256, 0, stream>>>(src, dst, E, al, gcursor, packed);
    k_proj      <<<(NN + 63) / 64, 256, 0, stream>>>(x, W1l, W1r, p1l16, p1r);
    k_agg1      <<<NBUCK, 256, 0, stream>>>(bbase, packed, p1l16, p1r, b1, h, h16, invdeg);
    k_final     <<<NBUCK, 256, 0, stream>>>(bbase, packed, h16, h, invdeg, W2l, b2, W2r, out);
}

// Round 7
// 539.987 us; speedup vs baseline: 1.0107x; 1.0107x over previous
//
#include <hip/hip_runtime.h>
#include <math.h>

constexpr int NN     = 100000;  // nodes
constexpr int DIN    = 128;
constexpr int DH     = 16;      // hidden
constexpr int NC     = 40;      // classes
constexpr int RNG    = 64;      // nodes per bucket (dst >> 6)
constexpr int NBUCK  = (NN + RNG - 1) / RNG;   // 1563
constexpr int NBUCKP = 2048;    // padded (power of 2 for scan)
constexpr int CHUNK  = 4096;    // edges per binscatter workgroup

__device__ __forceinline__ unsigned short f32_to_bf16(float f) {
    unsigned b = __float_as_uint(f);
    return (unsigned short)((b + 0x7FFFu + ((b >> 16) & 1u)) >> 16);
}
__device__ __forceinline__ float bf16u_to_f32(unsigned short u) {
    return __uint_as_float(((unsigned)u) << 16);
}

// ---------- pass 1: global bucket histogram ----------
__global__ void k_hist(const int* __restrict__ dst, int E, int al, int* __restrict__ ghist) {
    __shared__ int lh[NBUCKP];
    for (int i = threadIdx.x; i < NBUCKP; i += blockDim.x) lh[i] = 0;
    __syncthreads();
    int nv = al ? (E >> 2) : 0;
    const int4* d4 = (const int4*)dst;
    int i  = blockIdx.x * blockDim.x + threadIdx.x;
    int st = gridDim.x * blockDim.x;
    for (int k = i; k < nv; k += st) {
        int4 v = d4[k];
        atomicAdd(&lh[v.x >> 6], 1);
        atomicAdd(&lh[v.y >> 6], 1);
        atomicAdd(&lh[v.z >> 6], 1);
        atomicAdd(&lh[v.w >> 6], 1);
    }
    for (int e = 4 * nv + i; e < E; e += st) atomicAdd(&lh[dst[e] >> 6], 1);
    __syncthreads();
    for (int j = threadIdx.x; j < NBUCKP; j += blockDim.x) {
        int v = lh[j];
        if (v) atomicAdd(&ghist[j], v);
    }
}

// ---------- pass 2: exclusive scan of 2048 bucket counts (one WG, 1024 thr) ----------
__global__ __launch_bounds__(1024) void k_scan(const int* __restrict__ ghist,
                                               int* __restrict__ bbase,
                                               int* __restrict__ gcursor) {
    __shared__ int s[1024];
    int t = threadIdx.x;
    int a = ghist[2 * t], b = ghist[2 * t + 1];
    s[t] = a + b;
    __syncthreads();
    for (int o = 1; o < 1024; o <<= 1) {
        int v = (t >= o) ? s[t - o] : 0;
        __syncthreads();
        s[t] += v;
        __syncthreads();
    }
    int excl = t ? s[t - 1] : 0;
    bbase[2 * t]       = excl;
    gcursor[2 * t]     = excl;
    bbase[2 * t + 1]   = excl + a;
    gcursor[2 * t + 1] = excl + a;
    if (t == 1023) bbase[NBUCKP] = s[1023];
}

// ---------- pass 3: LDS counting-sort per chunk, coalesced writeout ----------
__global__ __launch_bounds__(256) void k_binscatter(
    const int* __restrict__ src, const int* __restrict__ dst, int E, int al,
    int* __restrict__ gcursor, unsigned* __restrict__ packed)
{
    __shared__ unsigned       spack[CHUNK];     // 16 KB
    __shared__ unsigned short sbuck[CHUNK];     // 8 KB
    __shared__ int lhist[NBUCKP];               // 8 KB
    __shared__ int lbase[NBUCKP];               // 8 KB
    __shared__ int part[256];

    int e0 = blockIdx.x * CHUNK;
    int cn = E - e0; if (cn > CHUNK) cn = CHUNK;
    int t = threadIdx.x;

    for (int i = t; i < NBUCKP; i += 256) lhist[i] = 0;
    __syncthreads();

    int nv = al ? (cn >> 2) : 0;
    const int4* dsp = (const int4*)(dst + e0);
    const int4* ssp = (const int4*)(src + e0);

    for (int i = t; i < nv; i += 256) {
        int4 v = dsp[i];
        atomicAdd(&lhist[v.x >> 6], 1);
        atomicAdd(&lhist[v.y >> 6], 1);
        atomicAdd(&lhist[v.z >> 6], 1);
        atomicAdd(&lhist[v.w >> 6], 1);
    }
    for (int i = 4 * nv + t; i < cn; i += 256) atomicAdd(&lhist[dst[e0 + i] >> 6], 1);
    __syncthreads();

    // per-thread scan of 8 owned buckets + block scan + global range claim
    int b8 = t * 8;
    int a[8], tot = 0;
    #pragma unroll
    for (int j = 0; j < 8; ++j) { a[j] = lhist[b8 + j]; tot += a[j]; }
    part[t] = tot;
    __syncthreads();
    for (int o = 1; o < 256; o <<= 1) {
        int v = (t >= o) ? part[t - o] : 0;
        __syncthreads();
        part[t] += v;
        __syncthreads();
    }
    int run = t ? part[t - 1] : 0;
    #pragma unroll
    for (int j = 0; j < 8; ++j) {
        int g = a[j] ? atomicAdd(&gcursor[b8 + j], a[j]) : 0;
        lbase[b8 + j] = g - run;
        lhist[b8 + j] = run;
        run += a[j];
    }
    __syncthreads();

    // counting-sort into LDS
    for (int i = t; i < nv; i += 256) {
        int4 dv = dsp[i];
        int4 sv = ssp[i];
        int d, b, pos;
        d = dv.x; b = d >> 6; pos = atomicAdd(&lhist[b], 1);
        spack[pos] = ((unsigned)(d & 63) << 20) | (unsigned)sv.x; sbuck[pos] = (unsigned short)b;
        d = dv.y; b = d >> 6; pos = atomicAdd(&lhist[b], 1);
        spack[pos] = ((unsigned)(d & 63) << 20) | (unsigned)sv.y; sbuck[pos] = (unsigned short)b;
        d = dv.z; b = d >> 6; pos = atomicAdd(&lhist[b], 1);
        spack[pos] = ((unsigned)(d & 63) << 20) | (unsigned)sv.z; sbuck[pos] = (unsigned short)b;
        d = dv.w; b = d >> 6; pos = atomicAdd(&lhist[b], 1);
        spack[pos] = ((unsigned)(d & 63) << 20) | (unsigned)sv.w; sbuck[pos] = (unsigned short)b;
    }
    for (int i = 4 * nv + t; i < cn; i += 256) {
        int d = dst[e0 + i], s = src[e0 + i];
        int b = d >> 6; int pos = atomicAdd(&lhist[b], 1);
        spack[pos] = ((unsigned)(d & 63) << 20) | (unsigned)s; sbuck[pos] = (unsigned short)b;
    }
    __syncthreads();

    for (int i = t; i < cn; i += 256)
        packed[lbase[sbuck[i]] + i] = spack[i];
}

// ---------- projection: LDS x-tile, coalesced; p1l -> bf16, p1r -> f32 ----------
__global__ __launch_bounds__(256) void k_proj(
    const float* __restrict__ x, const float* __restrict__ W1l, const float* __restrict__ W1r,
    unsigned short* __restrict__ p1l16, float* __restrict__ p1r)
{
    __shared__ float sX[64][DIN + 1];
    __shared__ float sW[DIN][32];
    int t  = threadIdx.x;
    int n0 = blockIdx.x * 64;
    for (int i = t; i < DIN * 32; i += 256) {
        int k = i >> 5, j = i & 31;
        sW[k][j] = (j < DH) ? W1l[k * DH + j] : W1r[k * DH + (j - DH)];
    }
    int nrow = NN - n0; if (nrow > 64) nrow = 64;
    const float4* xg = (const float4*)(x + (size_t)n0 * DIN);
    for (int i = t; i < nrow * (DIN / 4); i += 256) {
        float4 v = xg[i];
        int n = i >> 5, k = (i & 31) * 4;
        sX[n][k] = v.x; sX[n][k + 1] = v.y; sX[n][k + 2] = v.z; sX[n][k + 3] = v.w;
    }
    __syncthreads();
    int n = t & 63, jg = t >> 6;
    if (n0 + n >= NN) return;
    float acc[8];
    #pragma unroll
    for (int j = 0; j < 8; ++j) acc[j] = 0.f;
    const int j0 = jg * 8;
    for (int k = 0; k < DIN; ++k) {
        float xv = sX[n][k];
        const float4* wr = (const float4*)&sW[k][j0];
        float4 w0 = wr[0], w1 = wr[1];
        acc[0] = fmaf(xv, w0.x, acc[0]); acc[1] = fmaf(xv, w0.y, acc[1]);
        acc[2] = fmaf(xv, w0.z, acc[2]); acc[3] = fmaf(xv, w0.w, acc[3]);
        acc[4] = fmaf(xv, w1.x, acc[4]); acc[5] = fmaf(xv, w1.y, acc[5]);
        acc[6] = fmaf(xv, w1.z, acc[6]); acc[7] = fmaf(xv, w1.w, acc[7]);
    }
    size_t nn = (size_t)(n0 + n);
    if (jg < 2) {
        unsigned u0 = (unsigned)f32_to_bf16(acc[0]) | ((unsigned)f32_to_bf16(acc[1]) << 16);
        unsigned u1 = (unsigned)f32_to_bf16(acc[2]) | ((unsigned)f32_to_bf16(acc[3]) << 16);
        unsigned u2 = (unsigned)f32_to_bf16(acc[4]) | ((unsigned)f32_to_bf16(acc[5]) << 16);
        unsigned u3 = (unsigned)f32_to_bf16(acc[6]) | ((unsigned)f32_to_bf16(acc[7]) << 16);
        *(uint4*)(p1l16 + nn * DH + jg * 8) = make_uint4(u0, u1, u2, u3);
    } else {
        float* pp = p1r + nn * DH + (jg - 2) * 8;
        *(float4*)pp       = make_float4(acc[0], acc[1], acc[2], acc[3]);
        *(float4*)(pp + 4) = make_float4(acc[4], acc[5], acc[6], acc[7]);
    }
}

// ---------- layer-1 aggregate: thread-per-edge, x2 batch, 512 threads ----------
__global__ __launch_bounds__(512) void k_agg1(
    const int* __restrict__ bbase, const unsigned* __restrict__ packed,
    const unsigned short* __restrict__ p1l16, const float* __restrict__ p1r,
    const float* __restrict__ b1,
    float* __restrict__ h, unsigned short* __restrict__ h16, float* __restrict__ invdeg)
{
    __shared__ float agg[RNG][DH + 1];
    __shared__ int   ldeg[RNG];
    int b  = blockIdx.x;
    int n0 = b * RNG;
    int nr = NN - n0; if (nr > RNG) nr = RNG;
    int t = threadIdx.x;
    for (int i = t; i < RNG * (DH + 1); i += 512) (&agg[0][0])[i] = 0.f;
    if (t < RNG) ldeg[t] = 0;
    __syncthreads();
    int s0 = bbase[b], s1 = bbase[b + 1];
    int i = s0 + t;
    for (; i + 512 < s1; i += 1024) {
        unsigned pA = packed[i], pB = packed[i + 512];
        const uint4* rA = (const uint4*)(p1l16 + (size_t)(pA & 0xFFFFFu) * DH);
        const uint4* rB = (const uint4*)(p1l16 + (size_t)(pB & 0xFFFFFu) * DH);
        uint4 a0 = rA[0], a1 = rA[1], b0 = rB[0], b1v = rB[1];
        int dA = pA >> 20, dB = pB >> 20;
        atomicAdd(&ldeg[dA], 1);
        atomicAdd(&ldeg[dB], 1);
        float* fa = agg[dA];
        float* fb = agg[dB];
        unsigned wa[8] = {a0.x, a0.y, a0.z, a0.w, a1.x, a1.y, a1.z, a1.w};
        unsigned wb[8] = {b0.x, b0.y, b0.z, b0.w, b1v.x, b1v.y, b1v.z, b1v.w};
        #pragma unroll
        for (int j = 0; j < 8; ++j) {
            atomicAdd(&fa[2 * j],     __uint_as_float(wa[j] << 16));
            atomicAdd(&fa[2 * j + 1], __uint_as_float(wa[j] & 0xFFFF0000u));
            atomicAdd(&fb[2 * j],     __uint_as_float(wb[j] << 16));
            atomicAdd(&fb[2 * j + 1], __uint_as_float(wb[j] & 0xFFFF0000u));
        }
    }
    for (; i < s1; i += 512) {
        unsigned p = packed[i];
        const uint4* r = (const uint4*)(p1l16 + (size_t)(p & 0xFFFFFu) * DH);
        uint4 a0 = r[0], a1 = r[1];
        int dl = p >> 20;
        atomicAdd(&ldeg[dl], 1);
        float* fa = agg[dl];
        unsigned wa[8] = {a0.x, a0.y, a0.z, a0.w, a1.x, a1.y, a1.z, a1.w};
        #pragma unroll
        for (int j = 0; j < 8; ++j) {
            atomicAdd(&fa[2 * j],     __uint_as_float(wa[j] << 16));
            atomicAdd(&fa[2 * j + 1], __uint_as_float(wa[j] & 0xFFFF0000u));
        }
    }
    __syncthreads();
    for (int k = t; k < nr * DH; k += 512) {
        int nl = k >> 4, dd = k & 15;
        float inv = 1.0f / fmaxf((float)ldeg[nl], 1.0f);
        size_t n = (size_t)(n0 + nl);
        float v = fmaf(agg[nl][dd], inv, b1[dd] + p1r[n * DH + dd]);
        v = fmaxf(v, 0.f);
        h[n * DH + dd]   = v;
        h16[n * DH + dd] = f32_to_bf16(v);
        if (dd == 0) invdeg[n] = inv;
    }
}

// ---------- layer-2 aggregate + linear + log_softmax, 512 threads ----------
__global__ __launch_bounds__(512) void k_final(
    const int* __restrict__ bbase, const unsigned* __restrict__ packed,
    const unsigned short* __restrict__ h16, const float* __restrict__ h,
    const float* __restrict__ invdeg,
    const float* __restrict__ W2l, const float* __restrict__ b2,
    const float* __restrict__ W2r, float* __restrict__ out)
{
    __shared__ float agg[RNG][DH + 1];
    __shared__ float hloc[RNG][DH];
    __shared__ float sW[2 * DH * NC + NC];
    int t = threadIdx.x;
    for (int i = t; i < DH * NC; i += 512) { sW[i] = W2l[i]; sW[DH * NC + i] = W2r[i]; }
    if (t < NC) sW[2 * DH * NC + t] = b2[t];
    int b  = blockIdx.x;
    int n0 = b * RNG;
    int nr = NN - n0; if (nr > RNG) nr = RNG;
    for (int i = t; i < RNG * (DH + 1); i += 512) (&agg[0][0])[i] = 0.f;
    for (int i = t; i < nr * DH; i += 512) (&hloc[0][0])[i] = h[(size_t)n0 * DH + i];
    __syncthreads();
    int s0 = bbase[b], s1 = bbase[b + 1];
    int i = s0 + t;
    for (; i + 512 < s1; i += 1024) {
        unsigned pA = packed[i], pB = packed[i + 512];
        const uint4* rA = (const uint4*)(h16 + (size_t)(pA & 0xFFFFFu) * DH);
        const uint4* rB = (const uint4*)(h16 + (size_t)(pB & 0xFFFFFu) * DH);
        uint4 a0 = rA[0], a1 = rA[1], b0 = rB[0], b1v = rB[1];
        float* fa = agg[pA >> 20];
        float* fb = agg[pB >> 20];
        unsigned wa[8] = {a0.x, a0.y, a0.z, a0.w, a1.x, a1.y, a1.z, a1.w};
        unsigned wb[8] = {b0.x, b0.y, b0.z, b0.w, b1v.x, b1v.y, b1v.z, b1v.w};
        #pragma unroll
        for (int j = 0; j < 8; ++j) {
            atomicAdd(&fa[2 * j],     __uint_as_float(wa[j] << 16));
            atomicAdd(&fa[2 * j + 1], __uint_as_float(wa[j] & 0xFFFF0000u));
            atomicAdd(&fb[2 * j],     __uint_as_float(wb[j] << 16));
            atomicAdd(&fb[2 * j + 1], __uint_as_float(wb[j] & 0xFFFF0000u));
        }
    }
    for (; i < s1; i += 512) {
        unsigned p = packed[i];
        const uint4* r = (const uint4*)(h16 + (size_t)(p & 0xFFFFFu) * DH);
        uint4 a0 = r[0], a1 = r[1];
        float* fa = agg[p >> 20];
        unsigned wa[8] = {a0.x, a0.y, a0.z, a0.w, a1.x, a1.y, a1.z, a1.w};
        #pragma unroll
        for (int j = 0; j < 8; ++j) {
            atomicAdd(&fa[2 * j],     __uint_as_float(wa[j] << 16));
            atomicAdd(&fa[2 * j + 1], __uint_as_float(wa[j] & 0xFFFF0000u));
        }
    }
    __syncthreads();
    int wv = t >> 6, lane = t & 63;
    for (int nl = wv; nl < nr; nl += 8) {
        size_t n = (size_t)(n0 + nl);
        float inv = invdeg[n];
        int j = (lane < NC) ? lane : 0;
        float o = sW[2 * DH * NC + j];
        #pragma unroll
        for (int k = 0; k < DH; ++k) {
            float ak = agg[nl][k] * inv;
            float hk = hloc[nl][k];
            o = fmaf(ak, sW[k * NC + j],           o);
            o = fmaf(hk, sW[DH * NC + k * NC + j], o);
        }
        float mx = (lane < NC) ? o : -INFINITY;
        #pragma unroll
        for (int m = 32; m; m >>= 1) mx = fmaxf(mx, __shfl_xor(mx, m));
        float ex = (lane < NC) ? __expf(o - mx) : 0.f;
        float ss = ex;
        #pragma unroll
        for (int m = 32; m; m >>= 1) ss += __shfl_xor(ss, m);
        if (lane < NC) out[n * NC + lane] = o - mx - __logf(ss);
    }
}

// ---------------- launch ----------------

extern "C" void kernel_launch(void* const* d_in, const int* in_sizes, int n_in,
                              void* d_out, int out_size, void* d_ws, size_t ws_size,
                              hipStream_t stream) {
    const float* x   = (const float*)d_in[0];
    const int*   ei  = (const int*)d_in[1];   // [2, E] int32
    const float* W1l = (const float*)d_in[2];
    const float* b1  = (const float*)d_in[3];
    const float* W1r = (const float*)d_in[4];
    const float* W2l = (const float*)d_in[5];
    const float* b2  = (const float*)d_in[6];
    const float* W2r = (const float*)d_in[7];
    float* out = (float*)d_out;

    const int E = in_sizes[1] / 2;
    const int* src = ei;
    const int* dst = ei + E;
    const int al = ((E & 3) == 0) ? 1 : 0;

    // ws (4B words): ghist[2048] | gcursor[2048] | bbase[2056] | invdeg[NN] |
    //                packed[E] | p1r[16N] | h[16N] | p1l16(8N words) | h16(8N words)
    int* ghist   = (int*)d_ws;
    int* gcursor = ghist + NBUCKP;
    int* bbase   = gcursor + NBUCKP;
    float* invdeg = (float*)(bbase + NBUCKP + 8);
    unsigned* packed = (unsigned*)(invdeg + NN);
    float* p1r = (float*)(packed + E);
    float* h   = p1r + (size_t)NN * DH;
    unsigned short* p1l16 = (unsigned short*)(h + (size_t)NN * DH);
    unsigned short* h16   = p1l16 + (size_t)NN * DH;

    hipMemsetAsync(ghist, 0, NBUCKP * sizeof(int), stream);

    k_hist      <<<256, 256, 0, stream>>>(dst, E, al, ghist);
    k_scan      <<<1, 1024, 0, stream>>>(ghist, bbase, gcursor);
    k_binscatter<<<(E + CHUNK - 1) / CHUNK, 256, 0, stream>>>(src, dst, E, al, gcursor, packed);
    k_proj      <<<(NN + 63) / 64, 256, 0, stream>>>(x, W1l, W1r, p1l16, p1r);
    k_agg1      <<<NBUCK, 512, 0, stream>>>(bbase, packed, p1l16, p1r, b1, h, h16, invdeg);
    k_final     <<<NBUCK, 512, 0, stream>>>(bbase, packed, h16, h, invdeg, W2l, b2, W2r, out);
}

// Round 8
// 426.467 us; speedup vs baseline: 1.2797x; 1.2662x over previous
//
#include <hip/hip_runtime.h>
#include <math.h>

constexpr int NN  = 100000;  // nodes
constexpr int DIN = 128;
constexpr int DH  = 16;      // hidden
constexpr int NC  = 40;      // classes

// ---------- projection: LDS x-tile, coalesced; p1l, p1r f32 ----------
// [measured R7: this pattern ran fast enough to stay out of top-5]
__global__ __launch_bounds__(256) void k_proj(
    const float* __restrict__ x, const float* __restrict__ W1l, const float* __restrict__ W1r,
    float* __restrict__ p1l, float* __restrict__ p1r)
{
    __shared__ float sX[64][DIN + 1];
    __shared__ float sW[DIN][32];       // cols 0-15 = W1l, 16-31 = W1r
    int t  = threadIdx.x;
    int n0 = blockIdx.x * 64;
    for (int i = t; i < DIN * 32; i += 256) {
        int k = i >> 5, j = i & 31;
        sW[k][j] = (j < DH) ? W1l[k * DH + j] : W1r[k * DH + (j - DH)];
    }
    int nrow = NN - n0; if (nrow > 64) nrow = 64;
    const float4* xg = (const float4*)(x + (size_t)n0 * DIN);
    for (int i = t; i < nrow * (DIN / 4); i += 256) {
        float4 v = xg[i];
        int n = i >> 5, k = (i & 31) * 4;
        sX[n][k] = v.x; sX[n][k + 1] = v.y; sX[n][k + 2] = v.z; sX[n][k + 3] = v.w;
    }
    __syncthreads();
    int n = t & 63, jg = t >> 6;        // 4 col-groups of 8
    if (n0 + n >= NN) return;
    float acc[8];
    #pragma unroll
    for (int j = 0; j < 8; ++j) acc[j] = 0.f;
    const int j0 = jg * 8;
    for (int k = 0; k < DIN; ++k) {
        float xv = sX[n][k];                       // 2-way bank alias: free
        const float4* wr = (const float4*)&sW[k][j0];  // wave-uniform -> broadcast
        float4 w0 = wr[0], w1 = wr[1];
        acc[0] = fmaf(xv, w0.x, acc[0]); acc[1] = fmaf(xv, w0.y, acc[1]);
        acc[2] = fmaf(xv, w0.z, acc[2]); acc[3] = fmaf(xv, w0.w, acc[3]);
        acc[4] = fmaf(xv, w1.x, acc[4]); acc[5] = fmaf(xv, w1.y, acc[5]);
        acc[6] = fmaf(xv, w1.z, acc[6]); acc[7] = fmaf(xv, w1.w, acc[7]);
    }
    size_t nn = (size_t)(n0 + n);
    float* outp = (jg < 2) ? (p1l + nn * DH + jg * 8)
                           : (p1r + nn * DH + (jg - 2) * 8);
    *(float4*)outp       = make_float4(acc[0], acc[1], acc[2], acc[3]);
    *(float4*)(outp + 4) = make_float4(acc[4], acc[5], acc[6], acc[7]);
}

// ---------- edge-pass: agg[dst*16+d] += val[src*16+d]  (R1 layout, measured 85 us) ----------
// thread = (edge e, dim d): 16 CONTIGUOUS lanes per edge -> atomic instr's 64 lanes
// touch 4 whole 64-B lines (full line merging; the R2 lesson).
template <bool COUNT_DEG>
__global__ void k_scatter16(const int* __restrict__ src, const int* __restrict__ dst,
                            int E, const float* __restrict__ val,
                            float* __restrict__ agg, int* __restrict__ deg) {
    long gid   = (long)blockIdx.x * blockDim.x + threadIdx.x;
    long total = (long)E * DH;
    long st    = (long)gridDim.x * blockDim.x;
    for (; gid < total; gid += st) {
        int e = (int)(gid >> 4);
        int d = (int)(gid & 15);
        int s = src[e], dn = dst[e];
        unsafeAtomicAdd(agg + (long)dn * DH + d, val[(long)s * DH + d]);
        if (COUNT_DEG && d == 0) atomicAdd(deg + dn, 1);
    }
}

// ---------- h = relu(agg1/max(deg,1) + b1 + p1r)  (R2, measured fast) ----------
__global__ void k_hact(const float4* __restrict__ agg1, const int* __restrict__ deg,
                       const float* __restrict__ b1, const float4* __restrict__ p1r,
                       float4* __restrict__ h) {
    int i = blockIdx.x * blockDim.x + threadIdx.x;
    if (i >= NN * 4) return;
    int n = i >> 2, q = i & 3;
    float inv = 1.0f / fmaxf((float)deg[n], 1.0f);
    float4 a = agg1[i];
    float4 r = p1r[i];
    float4 b = *((const float4*)b1 + q);
    float4 o;
    o.x = fmaxf(fmaf(a.x, inv, b.x + r.x), 0.0f);
    o.y = fmaxf(fmaf(a.y, inv, b.y + r.y), 0.0f);
    o.z = fmaxf(fmaf(a.z, inv, b.z + r.z), 0.0f);
    o.w = fmaxf(fmaf(a.w, inv, b.w + r.w), 0.0f);
    h[i] = o;
}

// ---------- wave per node: out = log_softmax((aggh/deg)@W2l + b2 + h@W2r)  (R2) ----------
__global__ void k_final(const float* __restrict__ aggh, const int* __restrict__ deg,
                        const float* __restrict__ h,
                        const float* __restrict__ W2l, const float* __restrict__ b2,
                        const float* __restrict__ W2r, float* __restrict__ out) {
    __shared__ float sW[2 * DH * NC + NC];  // W2l | W2r | b2
    for (int i = threadIdx.x; i < DH * NC; i += blockDim.x) {
        sW[i]           = W2l[i];
        sW[DH * NC + i] = W2r[i];
    }
    if (threadIdx.x < NC) sW[2 * DH * NC + threadIdx.x] = b2[threadIdx.x];
    __syncthreads();

    int lane = threadIdx.x & 63;
    int n = (blockIdx.x * blockDim.x + threadIdx.x) >> 6;
    if (n >= NN) return;

    float rowv = 0.0f;
    if (lane < 32) {   // one VMEM instr loads the node's 32-float state
        const float* p = (lane < DH) ? (aggh + (long)n * DH + lane)
                                     : (h    + (long)n * DH + (lane - DH));
        rowv = *p;
    }
    float inv = 1.0f / fmaxf((float)deg[n], 1.0f);
    int j = (lane < NC) ? lane : 0;
    float o = sW[2 * DH * NC + j];
    #pragma unroll
    for (int k = 0; k < DH; ++k) {
        float ak = __shfl(rowv, k) * inv;
        float hk = __shfl(rowv, DH + k);
        o = fmaf(ak, sW[k * NC + j],           o);
        o = fmaf(hk, sW[DH * NC + k * NC + j], o);
    }
    float m = (lane < NC) ? o : -INFINITY;
    #pragma unroll
    for (int msk = 32; msk; msk >>= 1) m = fmaxf(m, __shfl_xor(m, msk));
    float ex = (lane < NC) ? __expf(o - m) : 0.0f;
    float s = ex;
    #pragma unroll
    for (int msk = 32; msk; msk >>= 1) s += __shfl_xor(s, msk);
    if (lane < NC) out[(long)n * NC + lane] = o - m - __logf(s);
}

// ---------------- launch ----------------

extern "C" void kernel_launch(void* const* d_in, const int* in_sizes, int n_in,
                              void* d_out, int out_size, void* d_ws, size_t ws_size,
                              hipStream_t stream) {
    const float* x   = (const float*)d_in[0];
    const int*   ei  = (const int*)d_in[1];   // [2, E] int32
    const float* W1l = (const float*)d_in[2];
    const float* b1  = (const float*)d_in[3];
    const float* W1r = (const float*)d_in[4];
    const float* W2l = (const float*)d_in[5];
    const float* b2  = (const float*)d_in[6];
    const float* W2r = (const float*)d_in[7];
    float* out = (float*)d_out;

    const int E = in_sizes[1] / 2;
    const int* src = ei;
    const int* dst = ei + E;

    // ws (4B words): deg[NN] | agg1[16N] | aggh[16N] | p1l[16N] | p1r[16N] | h[16N]
    float* ws   = (float*)d_ws;
    int*   deg  = (int*)ws;
    float* agg1 = ws + NN;
    float* aggh = agg1 + (size_t)16 * NN;
    float* p1l  = aggh + (size_t)16 * NN;
    float* p1r  = p1l + (size_t)16 * NN;
    float* h    = p1r + (size_t)16 * NN;

    // zero deg + agg1 + aggh in one memset
    hipMemsetAsync(d_ws, 0, (size_t)NN * 33 * sizeof(float), stream);

    k_proj<<<(NN + 63) / 64, 256, 0, stream>>>(x, W1l, W1r, p1l, p1r);
    k_scatter16<true ><<<2048, 256, 0, stream>>>(src, dst, E, p1l, agg1, deg);
    k_hact<<<(NN * 4 + 255) / 256, 256, 0, stream>>>((const float4*)agg1, deg, b1,
                                                     (const float4*)p1r, (float4*)h);
    k_scatter16<false><<<2048, 256, 0, stream>>>(src, dst, E, h, aggh, deg);
    k_final<<<(NN * 64 + 255) / 256, 256, 0, stream>>>(aggh, deg, h, W2l, b2, W2r, out);
}